// Round 1
// baseline (733.164 us; speedup 1.0000x reference)
//
#include <hip/hip_runtime.h>
#include <math.h>

#define DIN 128
#define DOUT 64
#define WROW 132            // padded LDS row stride (floats) for 64x128 tiles
#define GROW 65             // padded LDS row stride for 64x64 G

__device__ __forceinline__ float safe_pow(float d, float e) {
    float p = powf(d, e);
    return isinf(p) ? 0.0f : p;
}

// ---------------------------------------------------------------------------
// Kernel 1: Bjorck orthogonalization of W (DOUT x DIN), single workgroup.
//   w = W / (1.1 * sigma_max(W)); 5x: w = 1.5 w - 0.5 (w w^T) w
// ---------------------------------------------------------------------------
__device__ void compute_G(const float* w_s, float* g_s, int t) {
    for (int idx = t; idx < DOUT * DOUT; idx += 256) {
        int i = idx >> 6, j = idx & 63;
        const float4* a4 = (const float4*)&w_s[i * WROW];
        const float4* b4 = (const float4*)&w_s[j * WROW];
        float s = 0.f;
#pragma unroll
        for (int k = 0; k < DIN / 4; ++k) {
            float4 a = a4[k], b = b4[k];
            s += a.x * b.x + a.y * b.y + a.z * b.z + a.w * b.w;
        }
        g_s[i * GROW + j] = s;
    }
}

__global__ __launch_bounds__(256) void bjorck_kernel(const float* __restrict__ W,
                                                     float* __restrict__ Wo) {
    __shared__ float w_s[DOUT * WROW];
    __shared__ float t_s[DOUT * WROW];
    __shared__ float g_s[DOUT * GROW];
    __shared__ float sc_s;
    int t = threadIdx.x;

    for (int idx = t; idx < DOUT * DIN; idx += 256) {
        int i = idx >> 7, k = idx & 127;
        w_s[i * WROW + k] = W[idx];
    }
    __syncthreads();

    compute_G(w_s, g_s, t);
    __syncthreads();

    // power iteration on G (64x64 SPD) within wave 0; G row held in registers
    if (t < 64) {
        float grow_r[64];
#pragma unroll
        for (int j = 0; j < 64; ++j) grow_r[j] = g_s[t * GROW + j];
        unsigned h = (unsigned)t * 2654435761u;
        float x = 0.5f + (float)((h >> 17) & 0x7fff) * (1.0f / 32768.0f);
        float lam = 1.0f;
        for (int it = 0; it < 96; ++it) {
            float y = 0.f;
#pragma unroll
            for (int j = 0; j < 64; ++j) y += grow_r[j] * __shfl(x, j);
            float n2 = y * y;
#pragma unroll
            for (int d = 1; d < 64; d <<= 1) n2 += __shfl_xor(n2, d);
            lam = sqrtf(n2);        // ||G x|| with ||x||=1  -> lambda_max
            x = y / lam;
        }
        if (t == 0) sc_s = 1.0f / (1.1f * sqrtf(lam));   // sigma = sqrt(lambda)
    }
    __syncthreads();
    float sc = sc_s;
    for (int idx = t; idx < DOUT * DIN; idx += 256) {
        int i = idx >> 7, k = idx & 127;
        w_s[i * WROW + k] *= sc;
    }

    for (int iter = 0; iter < 5; ++iter) {
        __syncthreads();
        compute_G(w_s, g_s, t);
        __syncthreads();
        // T = G @ w  (float4 over columns)
        for (int idx = t; idx < DOUT * (DIN / 4); idx += 256) {
            int i = idx >> 5, c4 = idx & 31;
            float4 acc = make_float4(0.f, 0.f, 0.f, 0.f);
#pragma unroll
            for (int j = 0; j < 64; ++j) {
                float g = g_s[i * GROW + j];
                float4 wv = *(const float4*)&w_s[j * WROW + c4 * 4];
                acc.x += g * wv.x; acc.y += g * wv.y;
                acc.z += g * wv.z; acc.w += g * wv.w;
            }
            *(float4*)&t_s[i * WROW + c4 * 4] = acc;
        }
        __syncthreads();
        for (int idx = t; idx < DOUT * DIN; idx += 256) {
            int i = idx >> 7, k = idx & 127;
            w_s[i * WROW + k] = 1.5f * w_s[i * WROW + k] - 0.5f * t_s[i * WROW + k];
        }
    }
    __syncthreads();
    for (int idx = t; idx < DOUT * DIN; idx += 256) {
        int i = idx >> 7, k = idx & 127;
        Wo[idx] = w_s[i * WROW + k];
    }
}

// ---------------------------------------------------------------------------
// Kernel 2: per-node prep: d_e2m = m2*d^e2, d_e3 = d^e3,
//           gso2 = m1*d^e1 + m2*d^e2*d^e3 + m3
// ---------------------------------------------------------------------------
__global__ void node_prep(const float* __restrict__ diags,
                          const float* m1, const float* m2, const float* m3,
                          const float* e1, const float* e2, const float* e3,
                          float* __restrict__ d_e2m, float* __restrict__ d_e3p,
                          float* __restrict__ gso2, int n) {
    int i = blockIdx.x * blockDim.x + threadIdx.x;
    if (i >= n) return;
    float d = diags[i];
    float p1 = safe_pow(d, e1[0]);
    float p2 = safe_pow(d, e2[0]);
    float p3 = safe_pow(d, e3[0]);
    float vm2 = m2[0];
    d_e2m[i] = vm2 * p2;
    d_e3p[i] = p3;
    gso2[i] = m1[0] * p1 + vm2 * p2 * p3 + m3[0];
}

// ---------------------------------------------------------------------------
// Kernel 3: xw = x @ Wo^T   (N x DIN) x (DOUT x DIN)^T -> (N x DOUT)
// One 64-lane group per node; Wo staged in LDS (padded rows).
// ---------------------------------------------------------------------------
__global__ __launch_bounds__(256) void xw_kernel(const float* __restrict__ x,
                                                 const float* __restrict__ Wo,
                                                 float* __restrict__ xw, int n) {
    __shared__ float wo_s[DOUT * WROW];
    int t = threadIdx.x;
    for (int idx = t; idx < DOUT * DIN; idx += 256) {
        int i = idx >> 7, k = idx & 127;
        wo_s[i * WROW + k] = Wo[idx];
    }
    __syncthreads();
    int j = t & 63;
    int node = blockIdx.x * 4 + (t >> 6);
    if (node >= n) return;
    const float4* x4 = (const float4*)(x + (size_t)node * DIN);
    const float4* w4 = (const float4*)&wo_s[j * WROW];
    float acc = 0.f;
#pragma unroll
    for (int k = 0; k < DIN / 4; ++k) {
        float4 xv = x4[k], wv = w4[k];
        acc += xv.x * wv.x + xv.y * wv.y + xv.z * wv.z + xv.w * wv.w;
    }
    xw[(size_t)node * DOUT + j] = acc;
}

// ---------------------------------------------------------------------------
// Kernel 4: edge scatter: out[col] += (m2 * d^e2[row] * d^e3[col]) * xw[row]
// One 64-lane group per edge, grid-stride; atomic accumulate.
// ---------------------------------------------------------------------------
__global__ __launch_bounds__(256) void scatter_kernel(const int* __restrict__ ei,
                                                      const float* __restrict__ xw,
                                                      const float* __restrict__ d_e2m,
                                                      const float* __restrict__ d_e3p,
                                                      float* __restrict__ out, int e_cnt) {
    int lane = threadIdx.x & 63;
    int wave = blockIdx.x * 4 + (threadIdx.x >> 6);
    int nwaves = gridDim.x * 4;
    for (int e = wave; e < e_cnt; e += nwaves) {
        int row = ei[e];
        int col = ei[e_cnt + e];
        float w = d_e2m[row] * d_e3p[col];
        float v = w * xw[(size_t)row * DOUT + lane];
        atomicAdd(&out[(size_t)col * DOUT + lane], v);
    }
}

// ---------------------------------------------------------------------------
// Kernel 5: finalize: v = h_scatter + gso2[n]*xw[n] + 2*b; log_softmax over 64
// ---------------------------------------------------------------------------
__global__ __launch_bounds__(256) void finalize_kernel(const float* __restrict__ xw,
                                                       const float* __restrict__ gso2,
                                                       const float* __restrict__ b,
                                                       float* __restrict__ out, int n) {
    int lane = threadIdx.x & 63;
    int node = blockIdx.x * 4 + (threadIdx.x >> 6);
    if (node >= n) return;
    size_t off = (size_t)node * DOUT + lane;
    float v = out[off] + gso2[node] * xw[off] + 2.0f * b[lane];
    float m = v;
#pragma unroll
    for (int d = 1; d < 64; d <<= 1) m = fmaxf(m, __shfl_xor(m, d));
    float s = expf(v - m);
#pragma unroll
    for (int d = 1; d < 64; d <<= 1) s += __shfl_xor(s, d);
    out[off] = v - m - logf(s);
}

// ---------------------------------------------------------------------------
extern "C" void kernel_launch(void* const* d_in, const int* in_sizes, int n_in,
                              void* d_out, int out_size, void* d_ws, size_t ws_size,
                              hipStream_t stream) {
    const float* x     = (const float*)d_in[0];
    const int*   ei    = (const int*)d_in[1];
    // d_in[2] = edge_index_id (arange self loops) -> handled analytically
    const float* diags = (const float*)d_in[3];
    const float* W     = (const float*)d_in[4];
    const float* b     = (const float*)d_in[5];
    const float* m1    = (const float*)d_in[6];
    const float* m2    = (const float*)d_in[7];
    const float* m3    = (const float*)d_in[8];
    const float* e1    = (const float*)d_in[9];
    const float* e2    = (const float*)d_in[10];
    const float* e3    = (const float*)d_in[11];
    float* out = (float*)d_out;

    const int n = in_sizes[3];          // 100000 nodes
    const int e_cnt = in_sizes[1] / 2;  // 1600000 edges

    char* ws = (char*)d_ws;
    float* Wo    = (float*)ws;                        // 8192 f
    float* d_e2m = (float*)(ws + 32768);              // n f
    float* d_e3p = d_e2m + n;                         // n f
    float* gso2  = d_e3p + n;                         // n f
    float* xw    = gso2 + n;                          // n*64 f

    // out accumulates the edge scatter -> must start at zero every call
    hipMemsetAsync(d_out, 0, (size_t)out_size * sizeof(float), stream);

    bjorck_kernel<<<1, 256, 0, stream>>>(W, Wo);
    node_prep<<<(n + 255) / 256, 256, 0, stream>>>(diags, m1, m2, m3, e1, e2, e3,
                                                   d_e2m, d_e3p, gso2, n);
    xw_kernel<<<(n + 3) / 4, 256, 0, stream>>>(x, Wo, xw, n);
    scatter_kernel<<<4096, 256, 0, stream>>>(ei, xw, d_e2m, d_e3p, out, e_cnt);
    finalize_kernel<<<(n + 3) / 4, 256, 0, stream>>>(xw, gso2, b, out, n);
}